// Round 4
// baseline (493.677 us; speedup 1.0000x reference)
//
#include <hip/hip_runtime.h>
#include <hip/hip_bf16.h>
#include <math.h>

#define DIMK 1024
#define NH 16
#define HD 64
#define BB 4
#define SS 8192

typedef __attribute__((ext_vector_type(8))) short bf16x8;
typedef __attribute__((ext_vector_type(8))) unsigned short ushort8;
typedef __attribute__((ext_vector_type(4))) float f32x4;

#define MFMA16(a, b, c) __builtin_amdgcn_mfma_f32_16x16x32_bf16((a), (b), (c), 0, 0, 0)

__device__ __forceinline__ unsigned short f32_to_bf16_rne(float f) {
  unsigned int u = __float_as_uint(f);
  u = (u + 0x7fffu + ((u >> 16) & 1u)) >> 16;
  return (unsigned short)u;
}
__device__ __forceinline__ float bf16_bits_to_f32(unsigned short b) {
  return __uint_as_float(((unsigned int)b) << 16);
}

// ---------------- fill d_out with bo broadcast ----------------
__global__ __launch_bounds__(256) void fill_out_kernel(const float4* __restrict__ bo4,
                                                       float4* __restrict__ out, int total4) {
  for (int i = blockIdx.x * 256 + threadIdx.x; i < total4; i += gridDim.x * 256)
    out[i] = bo4[i & 255];  // DIMK/4 == 256
}

// ---------------- split W [k][n] fp32 -> WT_hi/WT_lo [n][k] bf16 ----------------
__global__ __launch_bounds__(256) void prep_w(const float* __restrict__ W,
                                              unsigned short* __restrict__ WT_hi,
                                              unsigned short* __restrict__ WT_lo) {
  __shared__ float st[64][65];
  const int bk = blockIdx.x * 64, bn = blockIdx.y * 64;
  const int t = threadIdx.x;
  const int lr = t >> 4, lc = (t & 15) * 4;
#pragma unroll
  for (int i = 0; i < 4; i++) {
    int k = lr + i * 16;
    float4 v = *(const float4*)(W + (size_t)(bk + k) * DIMK + bn + lc);
    st[k][lc] = v.x; st[k][lc + 1] = v.y; st[k][lc + 2] = v.z; st[k][lc + 3] = v.w;
  }
  __syncthreads();
#pragma unroll
  for (int i = 0; i < 4; i++) {
    int n = lr + i * 16;
    unsigned long long ph = 0, pl = 0;
#pragma unroll
    for (int j = 0; j < 4; j++) {
      float v = st[lc + j][n];
      unsigned short hb = f32_to_bf16_rne(v);
      unsigned short lb = f32_to_bf16_rne(v - bf16_bits_to_f32(hb));
      ph |= ((unsigned long long)hb) << (16 * j);
      pl |= ((unsigned long long)lb) << (16 * j);
    }
    *(unsigned long long*)(WT_hi + (size_t)(bn + n) * DIMK + bk + lc) = ph;
    *(unsigned long long*)(WT_lo + (size_t)(bn + n) * DIMK + bk + lc) = pl;
  }
}

// ---------------- gather rows of X, split fp32 -> bf16 hi/lo packed [M][DIMK] ----------------
__global__ __launch_bounds__(256) void prep_a(const float* __restrict__ X,
                                              const int* __restrict__ gidx,
                                              unsigned short* __restrict__ Ah,
                                              unsigned short* __restrict__ Al, int E) {
  const int row = blockIdx.x;
  const float* sr;
  if (gidx) {
    int b = row / E, e = row - b * E;
    sr = X + ((size_t)b * SS + gidx[e]) * DIMK;
  } else {
    sr = X + (size_t)row * DIMK;
  }
  const int d = threadIdx.x * 4;
  float4 v = *(const float4*)(sr + d);
  float vv[4] = {v.x, v.y, v.z, v.w};
  unsigned long long ph = 0, pl = 0;
#pragma unroll
  for (int i = 0; i < 4; i++) {
    unsigned short hb = f32_to_bf16_rne(vv[i]);
    unsigned short lb = f32_to_bf16_rne(vv[i] - bf16_bits_to_f32(hb));
    ph |= ((unsigned long long)hb) << (16 * i);
    pl |= ((unsigned long long)lb) << (16 * i);
  }
  *(unsigned long long*)(Ah + (size_t)row * DIMK + d) = ph;
  *(unsigned long long*)(Al + (size_t)row * DIMK + d) = pl;
}

// ---------------- first-occurrence map via atomicMin table ----------------
__global__ __launch_bounds__(256) void init_table(int* __restrict__ t) {
  t[blockIdx.x * 256 + threadIdx.x] = 0x7fffffff;
}
__global__ __launch_bounds__(256) void build_first(const int* __restrict__ src,
                                                   int* __restrict__ t, int E) {
  int e = blockIdx.x * 256 + threadIdx.x;
  if (e < E) atomicMin(&t[src[e]], e);
}
__global__ __launch_bounds__(256) void read_first(const int* __restrict__ src,
                                                  const int* __restrict__ t,
                                                  int* __restrict__ f, int E) {
  int e = blockIdx.x * 256 + threadIdx.x;
  if (e < E) f[e] = t[src[e]];
}

// ---------------- split-bf16 MFMA GEMM, pre-split A, XCD-swizzled tiles ----------------
// MODE 0: store out[m*ldc + n] = acc + bias_sel(n)
// MODE 1: store out[(b*SS+srci[e])*ldc + n] = acc + bias[n] iff fidx[e]==e
template <int MODE>
__global__ __launch_bounds__(256) void gemm_bf16p(
    const unsigned short* __restrict__ Ah, const unsigned short* __restrict__ Al,
    const unsigned short* __restrict__ BTh, const unsigned short* __restrict__ BTl,
    const float* __restrict__ bias, const float* __restrict__ bias2,
    float* __restrict__ out, int ldc, int gy,
    const int* __restrict__ fidx, const int* __restrict__ srci, int M, int E) {
  __shared__ unsigned short As_hi[128][40];
  __shared__ unsigned short As_lo[128][40];
  __shared__ unsigned short Bs_hi[128][40];
  __shared__ unsigned short Bs_lo[128][40];

  const int tid = threadIdx.x;
  // XCD-aware swizzle: blocks with consecutive w land on the same XCD; n-tiles
  // (sharing an A panel) are w-contiguous -> A panel stays in one L2.
  const int nwg = gridDim.x;
  int w;
  if ((nwg & 7) == 0)
    w = (blockIdx.x & 7) * (nwg >> 3) + (blockIdx.x >> 3);
  else
    w = blockIdx.x;
  const int mt = w / gy, nt = w - mt * gy;
  const int m0 = mt * 128, n0 = nt * 128;

  const int lane = tid & 63, wv = tid >> 6;
  const int wm0 = (wv >> 1) * 64, wn0 = (wv & 1) * 64;

  // staging: sweep s in {0,1}: l = s*256+tid; row = l>>2 (0..127), 16B quarter q = l&3
  const int r0 = tid >> 2, q0 = (tid & 3) * 8;
  const int r1 = r0 + 64;
  const size_t a0 = (size_t)((m0 + r0 < M) ? m0 + r0 : M - 1) * DIMK + q0;
  const size_t a1 = (size_t)((m0 + r1 < M) ? m0 + r1 : M - 1) * DIMK + q0;
  const unsigned short* pAh0 = Ah + a0;
  const unsigned short* pAh1 = Ah + a1;
  const unsigned short* pAl0 = Al + a0;
  const unsigned short* pAl1 = Al + a1;
  const size_t b0 = (size_t)(n0 + r0) * DIMK + q0;
  const size_t b1 = (size_t)(n0 + r1) * DIMK + q0;
  const unsigned short* pBh0 = BTh + b0;
  const unsigned short* pBh1 = BTh + b1;
  const unsigned short* pBl0 = BTl + b0;
  const unsigned short* pBl1 = BTl + b1;

  f32x4 acc[4][4];
#pragma unroll
  for (int i = 0; i < 4; i++)
#pragma unroll
    for (int j = 0; j < 4; j++) acc[i][j] = (f32x4){0.f, 0.f, 0.f, 0.f};

  for (int k0 = 0; k0 < DIMK; k0 += 32) {
    ushort8 vAh0 = *(const ushort8*)(pAh0 + k0);
    ushort8 vAh1 = *(const ushort8*)(pAh1 + k0);
    ushort8 vAl0 = *(const ushort8*)(pAl0 + k0);
    ushort8 vAl1 = *(const ushort8*)(pAl1 + k0);
    ushort8 vBh0 = *(const ushort8*)(pBh0 + k0);
    ushort8 vBh1 = *(const ushort8*)(pBh1 + k0);
    ushort8 vBl0 = *(const ushort8*)(pBl0 + k0);
    ushort8 vBl1 = *(const ushort8*)(pBl1 + k0);

    __syncthreads();
    *(ushort8*)&As_hi[r0][q0] = vAh0;
    *(ushort8*)&As_hi[r1][q0] = vAh1;
    *(ushort8*)&As_lo[r0][q0] = vAl0;
    *(ushort8*)&As_lo[r1][q0] = vAl1;
    *(ushort8*)&Bs_hi[r0][q0] = vBh0;
    *(ushort8*)&Bs_hi[r1][q0] = vBh1;
    *(ushort8*)&Bs_lo[r0][q0] = vBl0;
    *(ushort8*)&Bs_lo[r1][q0] = vBl1;
    __syncthreads();

    bf16x8 fah[4], fal[4], fbh[4], fbl[4];
    const int kk = (lane >> 4) * 8;
    const int rr = lane & 15;
#pragma unroll
    for (int f = 0; f < 4; f++) {
      fah[f] = *(bf16x8*)&As_hi[wm0 + f * 16 + rr][kk];
      fal[f] = *(bf16x8*)&As_lo[wm0 + f * 16 + rr][kk];
      fbh[f] = *(bf16x8*)&Bs_hi[wn0 + f * 16 + rr][kk];
      fbl[f] = *(bf16x8*)&Bs_lo[wn0 + f * 16 + rr][kk];
    }
#pragma unroll
    for (int mf = 0; mf < 4; mf++)
#pragma unroll
      for (int nf = 0; nf < 4; nf++) {
        acc[mf][nf] = MFMA16(fah[mf], fbh[nf], acc[mf][nf]);
        acc[mf][nf] = MFMA16(fah[mf], fbl[nf], acc[mf][nf]);
        acc[mf][nf] = MFMA16(fal[mf], fbh[nf], acc[mf][nf]);
      }
  }

  const int cq = lane >> 4, cr = lane & 15;
#pragma unroll
  for (int nf = 0; nf < 4; nf++) {
    const int col = n0 + wn0 + nf * 16 + cr;
    const float bv = (MODE == 0 && bias2 != nullptr && col >= DIMK) ? bias2[col - DIMK]
                                                                    : bias[col & (DIMK - 1)];
#pragma unroll
    for (int mf = 0; mf < 4; mf++) {
#pragma unroll
      for (int r = 0; r < 4; r++) {
        const int mrow = m0 + wm0 + mf * 16 + cq * 4 + r;
        if (mrow >= M) continue;
        if (MODE == 0) {
          out[(size_t)mrow * ldc + col] = acc[mf][nf][r] + bv;
        } else {
          int b = mrow / E, e = mrow - b * E;
          if (fidx[e] == e) {
            int orow = b * SS + srci[e];
            out[(size_t)orow * ldc + col] = acc[mf][nf][r] + bv;
          }
        }
      }
    }
  }
}

// ---------------- edge MLP scores: one wave per (b,h,e) ----------------
__global__ __launch_bounds__(256) void edge_scores(
    const float* __restrict__ qs, const float* __restrict__ kd, int ldk,
    const float* __restrict__ W1, const float* __restrict__ b1,
    const float* __restrict__ W2, const float* __restrict__ b2,
    float* __restrict__ scores, int E) {
  __shared__ float efs[4][128];
  const int w = threadIdx.x >> 6, lane = threadIdx.x & 63;
  const int eh = blockIdx.x * 4 + w;
  const int HE = NH * E;
  const int b = eh / HE;
  const int r = eh - b * HE;
  const int h = r / E;
  const int e = r - h * E;
  efs[w][lane] = qs[((size_t)(b * E + e)) * DIMK + h * HD + lane];
  efs[w][64 + lane] = kd[((size_t)(b * E + e)) * ldk + h * HD + lane];
  __syncthreads();
  float dot = 0.f;
#pragma unroll 16
  for (int i = 0; i < 128; i++) dot = fmaf(efs[w][i], W1[i * HD + lane], dot);
  float hv = dot + b1[lane];
  hv = 0.5f * hv * (1.f + erff(hv * 0.70710678118654752f));
  float p = hv * W2[lane];
#pragma unroll
  for (int off = 32; off; off >>= 1) p += __shfl_xor(p, off, 64);
  if (lane == 0) scores[(size_t)(b * NH + h) * E + e] = (p + b2[0]) * 0.125f;
}

// ---------------- softmax over E per (b,h), then *= edge_weight[h] ----------------
__global__ __launch_bounds__(256) void softmax_ew(float* __restrict__ scores,
                                                  const float* __restrict__ ew, int E) {
  const int row = blockIdx.x;
  const int h = row & (NH - 1);
  float* s = scores + (size_t)row * E;
  const int tid = threadIdx.x, lane = tid & 63, w = tid >> 6;
  __shared__ float red[4];

  float vals[8];
  float mx = -1e30f;
#pragma unroll
  for (int i = 0; i < 8; i++) {
    int j = tid + i * 256;
    vals[i] = (j < E) ? s[j] : -1e30f;
    mx = fmaxf(mx, vals[i]);
  }
#pragma unroll
  for (int off = 32; off; off >>= 1) mx = fmaxf(mx, __shfl_xor(mx, off, 64));
  if (lane == 0) red[w] = mx;
  __syncthreads();
  mx = fmaxf(fmaxf(red[0], red[1]), fmaxf(red[2], red[3]));
  __syncthreads();

  float sum = 0.f;
#pragma unroll
  for (int i = 0; i < 8; i++) {
    vals[i] = __expf(vals[i] - mx);
    if (tid + i * 256 < E) sum += vals[i];
  }
#pragma unroll
  for (int off = 32; off; off >>= 1) sum += __shfl_xor(sum, off, 64);
  if (lane == 0) red[w] = sum;
  __syncthreads();
  sum = red[0] + red[1] + red[2] + red[3];

  const float scaleout = ew[h] / sum;
#pragma unroll
  for (int i = 0; i < 8; i++) {
    int j = tid + i * 256;
    if (j < E) s[j] = vals[i] * scaleout;
  }
}

// ---------------- wrow[b*E+e][d] = attn[b,h(d),e] * vd[(b*E+e)*ldv + d] ----------------
__global__ __launch_bounds__(256) void weight_rows(const float* __restrict__ vd, int ldv,
                                                   const float* __restrict__ attn,
                                                   float* __restrict__ wrow, int E) {
  const int row = blockIdx.x;  // b*E + e
  const int b = row / E, e = row - b * E;
  const int d = threadIdx.x * 4;
  const int h = d >> 6;
  const float a = attn[(size_t)(b * NH + h) * E + e];
  float4 v = *(const float4*)(vd + (size_t)row * ldv + d);
  v.x *= a; v.y *= a; v.z *= a; v.w *= a;
  *(float4*)(wrow + (size_t)row * DIMK + d) = v;
}

// ---------------- fold duplicate-src edges into primary edge rows ----------------
__global__ __launch_bounds__(256) void dup_add(const int* __restrict__ f,
                                               float* __restrict__ wrow, int E) {
  const int e = blockIdx.x;
  const int fe = f[e];
  if (fe == e) return;
  const int d = threadIdx.x * 4;
#pragma unroll
  for (int b = 0; b < BB; b++) {
    const float4 v = *(const float4*)(wrow + (size_t)(b * E + e) * DIMK + d);
    float* dst = wrow + (size_t)(b * E + fe) * DIMK + d;
    atomicAdd(dst + 0, v.x);
    atomicAdd(dst + 1, v.y);
    atomicAdd(dst + 2, v.z);
    atomicAdd(dst + 3, v.w);
  }
}

extern "C" void kernel_launch(void* const* d_in, const int* in_sizes, int n_in,
                              void* d_out, int out_size, void* d_ws, size_t ws_size,
                              hipStream_t stream) {
  const float* x = (const float*)d_in[0];
  const int* src = (const int*)d_in[1];
  const int* dst = (const int*)d_in[2];
  const float* Wq = (const float*)d_in[3];
  const float* bq = (const float*)d_in[4];
  const float* Wk = (const float*)d_in[5];
  const float* bk = (const float*)d_in[6];
  const float* Wv = (const float*)d_in[7];
  const float* bv = (const float*)d_in[8];
  const float* Wo = (const float*)d_in[9];
  const float* bo = (const float*)d_in[10];
  const float* ew = (const float*)d_in[11];
  const float* W1 = (const float*)d_in[12];
  const float* b1 = (const float*)d_in[13];
  const float* W2 = (const float*)d_in[14];
  const float* b2 = (const float*)d_in[15];
  float* out = (float*)d_out;

  const int E = in_sizes[1];
  const int M = BB * E;

  char* w = (char*)d_ws;
  float* qs = (float*)w; w += (size_t)M * DIMK * 4;        // 32.8 MB (aliased by wrow later)
  float* kv = (float*)w; w += (size_t)M * 2048 * 4;        // 65.5 MB
  float* sc = (float*)w; w += (size_t)BB * NH * E * 4;
  int* table = (int*)w; w += (size_t)SS * 4;
  int* fidx = (int*)w; w += (((size_t)E * 4) + 255) & ~(size_t)255;
  const size_t WSZ = (size_t)DIMK * DIMK;
  unsigned short* WqT_hi = (unsigned short*)w;
  unsigned short* WqT_lo = WqT_hi + WSZ;
  unsigned short* WkvT_hi = WqT_lo + WSZ;       // 2048 rows
  unsigned short* WkvT_lo = WkvT_hi + 2 * WSZ;
  unsigned short* WoT_hi = WkvT_lo + 2 * WSZ;
  unsigned short* WoT_lo = WoT_hi + WSZ;
  unsigned short* Asp_h = WoT_lo + WSZ;         // shared gathered-A split, reused 3x
  unsigned short* Asp_l = Asp_h + (size_t)M * DIMK;

  float* wrow = qs;  // qs is dead after edge_scores

  // 1) fill output with bo
  const int total4 = BB * SS * (DIMK / 4);
  fill_out_kernel<<<2048, 256, 0, stream>>>((const float4*)bo, (float4*)out, total4);

  // 2) weight prep (split + transpose); Wk and Wv concatenated along N
  dim3 gw(16, 16);
  prep_w<<<gw, 256, 0, stream>>>(Wq, WqT_hi, WqT_lo);
  prep_w<<<gw, 256, 0, stream>>>(Wk, WkvT_hi, WkvT_lo);
  prep_w<<<gw, 256, 0, stream>>>(Wv, WkvT_hi + (size_t)1024 * DIMK, WkvT_lo + (size_t)1024 * DIMK);
  prep_w<<<gw, 256, 0, stream>>>(Wo, WoT_hi, WoT_lo);

  // 3) first-occurrence map (atomicMin table)
  init_table<<<SS / 256, 256, 0, stream>>>(table);
  build_first<<<(E + 255) / 256, 256, 0, stream>>>(src, table, E);
  read_first<<<(E + 255) / 256, 256, 0, stream>>>(src, table, fidx, E);

  const int gx = (M + 127) / 128;

  // 4) q projection: pre-split src-gathered A, then GEMM
  prep_a<<<M, 256, 0, stream>>>(x, src, Asp_h, Asp_l, E);
  gemm_bf16p<0><<<gx * 8, 256, 0, stream>>>(Asp_h, Asp_l, WqT_hi, WqT_lo, bq, nullptr, qs,
                                            DIMK, 8, nullptr, nullptr, M, E);

  // 5) fused k|v projection: pre-split dst-gathered A (reuse buffer), GEMM N=2048
  prep_a<<<M, 256, 0, stream>>>(x, dst, Asp_h, Asp_l, E);
  gemm_bf16p<0><<<gx * 16, 256, 0, stream>>>(Asp_h, Asp_l, WkvT_hi, WkvT_lo, bk, bv, kv,
                                             2048, 16, nullptr, nullptr, M, E);

  // 6) edge MLP -> scores (k at kv offset 0, stride 2048)
  edge_scores<<<(BB * NH * E) / 4, 256, 0, stream>>>(qs, kv, 2048, W1, b1, W2, b2, sc, E);

  // 7) softmax over edges + edge_weight
  softmax_ew<<<BB * NH, 256, 0, stream>>>(sc, ew, E);

  // 8) weighted rows (v at kv offset 1024), fold duplicates, split
  weight_rows<<<M, 256, 0, stream>>>(kv + 1024, 2048, sc, wrow, E);
  dup_add<<<E, 256, 0, stream>>>(fidx, wrow, E);
  prep_a<<<M, 256, 0, stream>>>(wrow, nullptr, Asp_h, Asp_l, E);

  // 9) final GEMM: wrow @ Wo, guarded scatter-store (no atomics)
  gemm_bf16p<1><<<gx * 8, 256, 0, stream>>>(Asp_h, Asp_l, WoT_hi, WoT_lo, bo, nullptr,
                                            out, DIMK, 8, fidx, src, M, E);
}

// Round 5
// 417.203 us; speedup vs baseline: 1.1833x; 1.1833x over previous
//
#include <hip/hip_runtime.h>
#include <hip/hip_bf16.h>
#include <math.h>

#define DIMK 1024
#define NH 16
#define HD 64
#define BB 4
#define SS 8192
#define EPAD 136

typedef __attribute__((ext_vector_type(8))) short bf16x8;
typedef __attribute__((ext_vector_type(8))) unsigned short ushort8;
typedef __attribute__((ext_vector_type(4))) float f32x4;

#define MFMA16(a, b, c) __builtin_amdgcn_mfma_f32_16x16x32_bf16((a), (b), (c), 0, 0, 0)

__device__ __forceinline__ unsigned short f32_to_bf16_rne(float f) {
  unsigned int u = __float_as_uint(f);
  u = (u + 0x7fffu + ((u >> 16) & 1u)) >> 16;
  return (unsigned short)u;
}
__device__ __forceinline__ float bf16_bits_to_f32(unsigned short b) {
  return __uint_as_float(((unsigned int)b) << 16);
}

// ---------------- fill d_out with bo broadcast ----------------
__global__ __launch_bounds__(256) void fill_out_kernel(const float4* __restrict__ bo4,
                                                       float4* __restrict__ out, int total4) {
  for (int i = blockIdx.x * 256 + threadIdx.x; i < total4; i += gridDim.x * 256)
    out[i] = bo4[i & 255];  // DIMK/4 == 256
}

// ---------------- split W [k][n] fp32 -> WT_hi/WT_lo [n][k] bf16 ----------------
__global__ __launch_bounds__(256) void prep_w(const float* __restrict__ W,
                                              unsigned short* __restrict__ WT_hi,
                                              unsigned short* __restrict__ WT_lo) {
  __shared__ float st[64][65];
  const int bk = blockIdx.x * 64, bn = blockIdx.y * 64;
  const int t = threadIdx.x;
  const int lr = t >> 4, lc = (t & 15) * 4;
#pragma unroll
  for (int i = 0; i < 4; i++) {
    int k = lr + i * 16;
    float4 v = *(const float4*)(W + (size_t)(bk + k) * DIMK + bn + lc);
    st[k][lc] = v.x; st[k][lc + 1] = v.y; st[k][lc + 2] = v.z; st[k][lc + 3] = v.w;
  }
  __syncthreads();
#pragma unroll
  for (int i = 0; i < 4; i++) {
    int n = lr + i * 16;
    unsigned long long ph = 0, pl = 0;
#pragma unroll
    for (int j = 0; j < 4; j++) {
      float v = st[lc + j][n];
      unsigned short hb = f32_to_bf16_rne(v);
      unsigned short lb = f32_to_bf16_rne(v - bf16_bits_to_f32(hb));
      ph |= ((unsigned long long)hb) << (16 * j);
      pl |= ((unsigned long long)lb) << (16 * j);
    }
    *(unsigned long long*)(WT_hi + (size_t)(bn + n) * DIMK + bk + lc) = ph;
    *(unsigned long long*)(WT_lo + (size_t)(bn + n) * DIMK + bk + lc) = pl;
  }
}

// ---------------- split W1 [128][64] fp32 -> W1T hi/lo [64][128] bf16 ----------------
__global__ __launch_bounds__(256) void prep_w1(const float* __restrict__ W1,
                                               unsigned short* __restrict__ W1Th,
                                               unsigned short* __restrict__ W1Tl) {
  for (int idx = threadIdx.x; idx < 128 * 64; idx += 256) {
    int k = idx >> 6, n = idx & 63;
    float v = W1[idx];
    unsigned short hb = f32_to_bf16_rne(v);
    unsigned short lb = f32_to_bf16_rne(v - bf16_bits_to_f32(hb));
    W1Th[n * 128 + k] = hb;
    W1Tl[n * 128 + k] = lb;
  }
}

// ---------------- gather rows of X, split fp32 -> bf16 hi/lo packed [M][DIMK] ----------------
__global__ __launch_bounds__(256) void prep_a(const float* __restrict__ X,
                                              const int* __restrict__ gidx,
                                              unsigned short* __restrict__ Ah,
                                              unsigned short* __restrict__ Al, int E) {
  const int row = blockIdx.x;
  const float* sr;
  if (gidx) {
    int b = row / E, e = row - b * E;
    sr = X + ((size_t)b * SS + gidx[e]) * DIMK;
  } else {
    sr = X + (size_t)row * DIMK;
  }
  const int d = threadIdx.x * 4;
  float4 v = *(const float4*)(sr + d);
  float vv[4] = {v.x, v.y, v.z, v.w};
  unsigned long long ph = 0, pl = 0;
#pragma unroll
  for (int i = 0; i < 4; i++) {
    unsigned short hb = f32_to_bf16_rne(vv[i]);
    unsigned short lb = f32_to_bf16_rne(vv[i] - bf16_bits_to_f32(hb));
    ph |= ((unsigned long long)hb) << (16 * i);
    pl |= ((unsigned long long)lb) << (16 * i);
  }
  *(unsigned long long*)(Ah + (size_t)row * DIMK + d) = ph;
  *(unsigned long long*)(Al + (size_t)row * DIMK + d) = pl;
}

// ---------------- first-occurrence map via atomicMin table ----------------
__global__ __launch_bounds__(256) void init_table(int* __restrict__ t) {
  t[blockIdx.x * 256 + threadIdx.x] = 0x7fffffff;
}
__global__ __launch_bounds__(256) void build_first(const int* __restrict__ src,
                                                   int* __restrict__ t, int E) {
  int e = blockIdx.x * 256 + threadIdx.x;
  if (e < E) atomicMin(&t[src[e]], e);
}
__global__ __launch_bounds__(256) void read_first(const int* __restrict__ src,
                                                  const int* __restrict__ t,
                                                  int* __restrict__ f, int E) {
  int e = blockIdx.x * 256 + threadIdx.x;
  if (e < E) f[e] = t[src[e]];
}

// ---------------- split-bf16 MFMA GEMM, pre-split A, XCD-swizzled tiles ----------------
template <int MODE>
__global__ __launch_bounds__(256) void gemm_bf16p(
    const unsigned short* __restrict__ Ah, const unsigned short* __restrict__ Al,
    const unsigned short* __restrict__ BTh, const unsigned short* __restrict__ BTl,
    const float* __restrict__ bias, const float* __restrict__ bias2,
    float* __restrict__ out, int ldc, int gy,
    const int* __restrict__ fidx, const int* __restrict__ srci, int M, int E) {
  __shared__ unsigned short As_hi[128][40];
  __shared__ unsigned short As_lo[128][40];
  __shared__ unsigned short Bs_hi[128][40];
  __shared__ unsigned short Bs_lo[128][40];

  const int tid = threadIdx.x;
  const int nwg = gridDim.x;
  int w;
  if ((nwg & 7) == 0)
    w = (blockIdx.x & 7) * (nwg >> 3) + (blockIdx.x >> 3);
  else
    w = blockIdx.x;
  const int mt = w / gy, nt = w - mt * gy;
  const int m0 = mt * 128, n0 = nt * 128;

  const int lane = tid & 63, wv = tid >> 6;
  const int wm0 = (wv >> 1) * 64, wn0 = (wv & 1) * 64;

  const int r0 = tid >> 2, q0 = (tid & 3) * 8;
  const int r1 = r0 + 64;
  const size_t a0 = (size_t)((m0 + r0 < M) ? m0 + r0 : M - 1) * DIMK + q0;
  const size_t a1 = (size_t)((m0 + r1 < M) ? m0 + r1 : M - 1) * DIMK + q0;
  const unsigned short* pAh0 = Ah + a0;
  const unsigned short* pAh1 = Ah + a1;
  const unsigned short* pAl0 = Al + a0;
  const unsigned short* pAl1 = Al + a1;
  const size_t b0 = (size_t)(n0 + r0) * DIMK + q0;
  const size_t b1 = (size_t)(n0 + r1) * DIMK + q0;
  const unsigned short* pBh0 = BTh + b0;
  const unsigned short* pBh1 = BTh + b1;
  const unsigned short* pBl0 = BTl + b0;
  const unsigned short* pBl1 = BTl + b1;

  f32x4 acc[4][4];
#pragma unroll
  for (int i = 0; i < 4; i++)
#pragma unroll
    for (int j = 0; j < 4; j++) acc[i][j] = (f32x4){0.f, 0.f, 0.f, 0.f};

  for (int k0 = 0; k0 < DIMK; k0 += 32) {
    ushort8 vAh0 = *(const ushort8*)(pAh0 + k0);
    ushort8 vAh1 = *(const ushort8*)(pAh1 + k0);
    ushort8 vAl0 = *(const ushort8*)(pAl0 + k0);
    ushort8 vAl1 = *(const ushort8*)(pAl1 + k0);
    ushort8 vBh0 = *(const ushort8*)(pBh0 + k0);
    ushort8 vBh1 = *(const ushort8*)(pBh1 + k0);
    ushort8 vBl0 = *(const ushort8*)(pBl0 + k0);
    ushort8 vBl1 = *(const ushort8*)(pBl1 + k0);

    __syncthreads();
    *(ushort8*)&As_hi[r0][q0] = vAh0;
    *(ushort8*)&As_hi[r1][q0] = vAh1;
    *(ushort8*)&As_lo[r0][q0] = vAl0;
    *(ushort8*)&As_lo[r1][q0] = vAl1;
    *(ushort8*)&Bs_hi[r0][q0] = vBh0;
    *(ushort8*)&Bs_hi[r1][q0] = vBh1;
    *(ushort8*)&Bs_lo[r0][q0] = vBl0;
    *(ushort8*)&Bs_lo[r1][q0] = vBl1;
    __syncthreads();

    bf16x8 fah[4], fal[4], fbh[4], fbl[4];
    const int kk = (lane >> 4) * 8;
    const int rr = lane & 15;
#pragma unroll
    for (int f = 0; f < 4; f++) {
      fah[f] = *(bf16x8*)&As_hi[wm0 + f * 16 + rr][kk];
      fal[f] = *(bf16x8*)&As_lo[wm0 + f * 16 + rr][kk];
      fbh[f] = *(bf16x8*)&Bs_hi[wn0 + f * 16 + rr][kk];
      fbl[f] = *(bf16x8*)&Bs_lo[wn0 + f * 16 + rr][kk];
    }
#pragma unroll
    for (int mf = 0; mf < 4; mf++)
#pragma unroll
      for (int nf = 0; nf < 4; nf++) {
        acc[mf][nf] = MFMA16(fah[mf], fbh[nf], acc[mf][nf]);
        acc[mf][nf] = MFMA16(fah[mf], fbl[nf], acc[mf][nf]);
        acc[mf][nf] = MFMA16(fal[mf], fbh[nf], acc[mf][nf]);
      }
  }

  const int cq = lane >> 4, cr = lane & 15;
#pragma unroll
  for (int nf = 0; nf < 4; nf++) {
    const int col = n0 + wn0 + nf * 16 + cr;
    const float bv = (MODE == 0 && bias2 != nullptr && col >= DIMK) ? bias2[col - DIMK]
                                                                    : bias[col & (DIMK - 1)];
#pragma unroll
    for (int mf = 0; mf < 4; mf++) {
#pragma unroll
      for (int r = 0; r < 4; r++) {
        const int mrow = m0 + wm0 + mf * 16 + cq * 4 + r;
        if (mrow >= M) continue;
        if (MODE == 0) {
          out[(size_t)mrow * ldc + col] = acc[mf][nf][r] + bv;
        } else {
          int b = mrow / E, e = mrow - b * E;
          if (fidx[e] == e) {
            int orow = b * SS + srci[e];
            out[(size_t)orow * ldc + col] = acc[mf][nf][r] + bv;
          }
        }
      }
    }
  }
}

// ---------------- edge MLP scores via MFMA ----------------
// One wave per 16-edge tile; W1T(hi/lo) LDS-staged per block; 3-term bf16 split.
__global__ __launch_bounds__(256) void edge_scores_mfma(
    const float* __restrict__ qs, const float* __restrict__ kd, int ldk,
    const unsigned short* __restrict__ W1Th, const unsigned short* __restrict__ W1Tl,
    const float* __restrict__ b1, const float* __restrict__ W2,
    const float* __restrict__ b2, float* __restrict__ scores, int E, int CH) {
  __shared__ unsigned short W1h[64][EPAD], W1l[64][EPAD];
  __shared__ unsigned short EFh[4][16][EPAD], EFl[4][16][EPAD];
  const int tid = threadIdx.x, lane = tid & 63, w = tid >> 6;
  const int bh = blockIdx.x / CH, ch = blockIdx.x - bh * CH;
  const int b = bh >> 4, h = bh & 15;

  // stage W1T into LDS (all threads)
  for (int idx = tid; idx < 64 * 16; idx += 256) {
    int n = idx >> 4, g = (idx & 15) * 8;
    *(ushort8*)&W1h[n][g] = *(const ushort8*)(W1Th + n * 128 + g);
    *(ushort8*)&W1l[n][g] = *(const ushort8*)(W1Tl + n * 128 + g);
  }
  __syncthreads();

  const int etile = ch * 4 + w;
  const int e0 = etile * 16;
  if (e0 >= E) return;

  // stage EF rows (wave-local): lane covers row r, 16 cols at c0
  const int r = lane >> 2, c0 = (lane & 3) * 16;
  {
    const int er = (e0 + r < E) ? e0 + r : E - 1;
    const float* qrow = qs + ((size_t)(b * E + er)) * DIMK + h * HD + c0;
    const float* krow = kd + ((size_t)(b * E + er)) * (size_t)ldk + h * HD + c0;
    float qv[16], kvv[16];
#pragma unroll
    for (int i = 0; i < 4; i++) {
      *(float4*)&qv[i * 4] = *(const float4*)(qrow + i * 4);
      *(float4*)&kvv[i * 4] = *(const float4*)(krow + i * 4);
    }
    ushort8 qh[2], ql[2], kh[2], kl[2];
#pragma unroll
    for (int g = 0; g < 2; g++)
#pragma unroll
      for (int i = 0; i < 8; i++) {
        float v = qv[g * 8 + i];
        unsigned short hb = f32_to_bf16_rne(v);
        qh[g][i] = hb;
        ql[g][i] = f32_to_bf16_rne(v - bf16_bits_to_f32(hb));
        float v2 = kvv[g * 8 + i];
        unsigned short hb2 = f32_to_bf16_rne(v2);
        kh[g][i] = hb2;
        kl[g][i] = f32_to_bf16_rne(v2 - bf16_bits_to_f32(hb2));
      }
    *(ushort8*)&EFh[w][r][c0] = qh[0];
    *(ushort8*)&EFh[w][r][c0 + 8] = qh[1];
    *(ushort8*)&EFl[w][r][c0] = ql[0];
    *(ushort8*)&EFl[w][r][c0 + 8] = ql[1];
    *(ushort8*)&EFh[w][r][64 + c0] = kh[0];
    *(ushort8*)&EFh[w][r][64 + c0 + 8] = kh[1];
    *(ushort8*)&EFl[w][r][64 + c0] = kl[0];
    *(ushort8*)&EFl[w][r][64 + c0 + 8] = kl[1];
  }
  // wave-local LDS dependency: ensure writes land before frag reads
  asm volatile("s_waitcnt lgkmcnt(0)" ::: "memory");
  __builtin_amdgcn_sched_barrier(0);

  f32x4 acc[4];
#pragma unroll
  for (int i = 0; i < 4; i++) acc[i] = (f32x4){0.f, 0.f, 0.f, 0.f};

  const int kk = (lane >> 4) * 8, rr = lane & 15;
#pragma unroll
  for (int ks = 0; ks < 4; ks++) {
    bf16x8 ah = *(bf16x8*)&EFh[w][rr][ks * 32 + kk];
    bf16x8 al = *(bf16x8*)&EFl[w][rr][ks * 32 + kk];
#pragma unroll
    for (int nf = 0; nf < 4; nf++) {
      bf16x8 bh_ = *(bf16x8*)&W1h[nf * 16 + rr][ks * 32 + kk];
      bf16x8 bl_ = *(bf16x8*)&W1l[nf * 16 + rr][ks * 32 + kk];
      acc[nf] = MFMA16(ah, bh_, acc[nf]);
      acc[nf] = MFMA16(ah, bl_, acc[nf]);
      acc[nf] = MFMA16(al, bh_, acc[nf]);
    }
  }

  // epilogue: h -> gelu -> @W2; C layout col=lane&15, row=(lane>>4)*4+r
  const int col_l = lane & 15, rq = lane >> 4;
  float w2v[4], b1v[4];
#pragma unroll
  for (int nf = 0; nf < 4; nf++) {
    w2v[nf] = W2[nf * 16 + col_l];
    b1v[nf] = b1[nf * 16 + col_l];
  }
  float p[4];
#pragma unroll
  for (int rr2 = 0; rr2 < 4; rr2++) {
    float s = 0.f;
#pragma unroll
    for (int nf = 0; nf < 4; nf++) {
      float hv = acc[nf][rr2] + b1v[nf];
      hv = 0.5f * hv * (1.f + erff(hv * 0.70710678118654752f));
      s = fmaf(hv, w2v[nf], s);
    }
    p[rr2] = s;
  }
#pragma unroll
  for (int off = 1; off < 16; off <<= 1)
#pragma unroll
    for (int rr2 = 0; rr2 < 4; rr2++) p[rr2] += __shfl_xor(p[rr2], off, 64);

  if (col_l == 0) {
    const float b2v = b2[0];
#pragma unroll
    for (int rr2 = 0; rr2 < 4; rr2++) {
      int e = e0 + rq * 4 + rr2;
      if (e < E) scores[(size_t)(b * NH + h) * E + e] = (p[rr2] + b2v) * 0.125f;
    }
  }
}

// ---------------- softmax over E per (b,h), then *= edge_weight[h] ----------------
__global__ __launch_bounds__(256) void softmax_ew(float* __restrict__ scores,
                                                  const float* __restrict__ ew, int E) {
  const int row = blockIdx.x;
  const int h = row & (NH - 1);
  float* s = scores + (size_t)row * E;
  const int tid = threadIdx.x, lane = tid & 63, w = tid >> 6;
  __shared__ float red[4];

  float vals[8];
  float mx = -1e30f;
#pragma unroll
  for (int i = 0; i < 8; i++) {
    int j = tid + i * 256;
    vals[i] = (j < E) ? s[j] : -1e30f;
    mx = fmaxf(mx, vals[i]);
  }
#pragma unroll
  for (int off = 32; off; off >>= 1) mx = fmaxf(mx, __shfl_xor(mx, off, 64));
  if (lane == 0) red[w] = mx;
  __syncthreads();
  mx = fmaxf(fmaxf(red[0], red[1]), fmaxf(red[2], red[3]));
  __syncthreads();

  float sum = 0.f;
#pragma unroll
  for (int i = 0; i < 8; i++) {
    vals[i] = __expf(vals[i] - mx);
    if (tid + i * 256 < E) sum += vals[i];
  }
#pragma unroll
  for (int off = 32; off; off >>= 1) sum += __shfl_xor(sum, off, 64);
  if (lane == 0) red[w] = sum;
  __syncthreads();
  sum = red[0] + red[1] + red[2] + red[3];

  const float scaleout = ew[h] / sum;
#pragma unroll
  for (int i = 0; i < 8; i++) {
    int j = tid + i * 256;
    if (j < E) s[j] = vals[i] * scaleout;
  }
}

// ---------------- wrow[b*E+e][d] = attn[b,h(d),e] * vd[(b*E+e)*ldv + d] ----------------
__global__ __launch_bounds__(256) void weight_rows(const float* __restrict__ vd, int ldv,
                                                   const float* __restrict__ attn,
                                                   float* __restrict__ wrow, int E) {
  const int row = blockIdx.x;  // b*E + e
  const int b = row / E, e = row - b * E;
  const int d = threadIdx.x * 4;
  const int h = d >> 6;
  const float a = attn[(size_t)(b * NH + h) * E + e];
  float4 v = *(const float4*)(vd + (size_t)row * ldv + d);
  v.x *= a; v.y *= a; v.z *= a; v.w *= a;
  *(float4*)(wrow + (size_t)row * DIMK + d) = v;
}

// ---------------- fold duplicate-src edges into primary edge rows ----------------
__global__ __launch_bounds__(256) void dup_add(const int* __restrict__ f,
                                               float* __restrict__ wrow, int E) {
  const int e = blockIdx.x;
  const int fe = f[e];
  if (fe == e) return;
  const int d = threadIdx.x * 4;
#pragma unroll
  for (int b = 0; b < BB; b++) {
    const float4 v = *(const float4*)(wrow + (size_t)(b * E + e) * DIMK + d);
    float* dst = wrow + (size_t)(b * E + fe) * DIMK + d;
    atomicAdd(dst + 0, v.x);
    atomicAdd(dst + 1, v.y);
    atomicAdd(dst + 2, v.z);
    atomicAdd(dst + 3, v.w);
  }
}

extern "C" void kernel_launch(void* const* d_in, const int* in_sizes, int n_in,
                              void* d_out, int out_size, void* d_ws, size_t ws_size,
                              hipStream_t stream) {
  const float* x = (const float*)d_in[0];
  const int* src = (const int*)d_in[1];
  const int* dst = (const int*)d_in[2];
  const float* Wq = (const float*)d_in[3];
  const float* bq = (const float*)d_in[4];
  const float* Wk = (const float*)d_in[5];
  const float* bk = (const float*)d_in[6];
  const float* Wv = (const float*)d_in[7];
  const float* bv = (const float*)d_in[8];
  const float* Wo = (const float*)d_in[9];
  const float* bo = (const float*)d_in[10];
  const float* ew = (const float*)d_in[11];
  const float* W1 = (const float*)d_in[12];
  const float* b1 = (const float*)d_in[13];
  const float* W2 = (const float*)d_in[14];
  const float* b2 = (const float*)d_in[15];
  float* out = (float*)d_out;

  const int E = in_sizes[1];
  const int M = BB * E;

  char* w = (char*)d_ws;
  float* qs = (float*)w; w += (size_t)M * DIMK * 4;
  float* kv = (float*)w; w += (size_t)M * 2048 * 4;
  float* sc = (float*)w; w += (size_t)BB * NH * E * 4;
  int* table = (int*)w; w += (size_t)SS * 4;
  int* fidx = (int*)w; w += (((size_t)E * 4) + 255) & ~(size_t)255;
  const size_t WSZ = (size_t)DIMK * DIMK;
  unsigned short* WqT_hi = (unsigned short*)w;
  unsigned short* WqT_lo = WqT_hi + WSZ;
  unsigned short* WkvT_hi = WqT_lo + WSZ;
  unsigned short* WkvT_lo = WkvT_hi + 2 * WSZ;
  unsigned short* WoT_hi = WkvT_lo + 2 * WSZ;
  unsigned short* WoT_lo = WoT_hi + WSZ;
  unsigned short* Asp_h = WoT_lo + WSZ;
  unsigned short* Asp_l = Asp_h + (size_t)M * DIMK;
  unsigned short* W1Th = Asp_l + (size_t)M * DIMK;
  unsigned short* W1Tl = W1Th + 64 * 128;

  float* wrow = qs;  // qs dead after edge_scores

  // 1) fill output with bo
  const int total4 = BB * SS * (DIMK / 4);
  fill_out_kernel<<<2048, 256, 0, stream>>>((const float4*)bo, (float4*)out, total4);

  // 2) weight prep (split + transpose); Wk|Wv concatenated along N; W1 for edge MLP
  dim3 gw(16, 16);
  prep_w<<<gw, 256, 0, stream>>>(Wq, WqT_hi, WqT_lo);
  prep_w<<<gw, 256, 0, stream>>>(Wk, WkvT_hi, WkvT_lo);
  prep_w<<<gw, 256, 0, stream>>>(Wv, WkvT_hi + (size_t)1024 * DIMK, WkvT_lo + (size_t)1024 * DIMK);
  prep_w<<<gw, 256, 0, stream>>>(Wo, WoT_hi, WoT_lo);
  prep_w1<<<1, 256, 0, stream>>>(W1, W1Th, W1Tl);

  // 3) first-occurrence map (atomicMin table)
  init_table<<<SS / 256, 256, 0, stream>>>(table);
  build_first<<<(E + 255) / 256, 256, 0, stream>>>(src, table, E);
  read_first<<<(E + 255) / 256, 256, 0, stream>>>(src, table, fidx, E);

  const int gx = (M + 127) / 128;

  // 4) q projection
  prep_a<<<M, 256, 0, stream>>>(x, src, Asp_h, Asp_l, E);
  gemm_bf16p<0><<<gx * 8, 256, 0, stream>>>(Asp_h, Asp_l, WqT_hi, WqT_lo, bq, nullptr, qs,
                                            DIMK, 8, nullptr, nullptr, M, E);

  // 5) fused k|v projection
  prep_a<<<M, 256, 0, stream>>>(x, dst, Asp_h, Asp_l, E);
  gemm_bf16p<0><<<gx * 16, 256, 0, stream>>>(Asp_h, Asp_l, WkvT_hi, WkvT_lo, bk, bv, kv,
                                             2048, 16, nullptr, nullptr, M, E);

  // 6) edge MLP -> scores (MFMA; k at kv offset 0, stride 2048)
  const int etiles = (E + 15) / 16;
  const int CH = (etiles + 3) / 4;
  edge_scores_mfma<<<BB * NH * CH, 256, 0, stream>>>(qs, kv, 2048, W1Th, W1Tl, b1, W2, b2,
                                                     sc, E, CH);

  // 7) softmax over edges + edge_weight
  softmax_ew<<<BB * NH, 256, 0, stream>>>(sc, ew, E);

  // 8) weighted rows (v at kv offset 1024), fold duplicates, split
  weight_rows<<<M, 256, 0, stream>>>(kv + 1024, 2048, sc, wrow, E);
  dup_add<<<E, 256, 0, stream>>>(fidx, wrow, E);
  prep_a<<<M, 256, 0, stream>>>(wrow, nullptr, Asp_h, Asp_l, E);

  // 9) final GEMM: wrow @ Wo, guarded scatter-store
  gemm_bf16p<1><<<gx * 8, 256, 0, stream>>>(Asp_h, Asp_l, WoT_hi, WoT_lo, bo, nullptr,
                                            out, DIMK, 8, fidx, src, M, E);
}